// Round 11
// baseline (2981.152 us; speedup 1.0000x reference)
//
#include <hip/hip_runtime.h>
#include <hip/hip_bf16.h>

// ---------------------------------------------------------------------------
// Encoder: emb gather -> LSTM0 -> LSTM1 -> BatchNorm(inference)
// B=64, T=128, D=256, H=1024, 4H=4096, BT=8192 rows.
//
// Round-11 structure: WAVE-PER-CHAIN decoupled recurrence.
//  - r6-r10 lesson: lockstep grid barriers pin the step at ~6.4us (serial
//    drain -> RMW -> poll -> load round-trips). Fix: batch rows = 4
//    INDEPENDENT 16-row chains; wave w of every WG owns chain w. The 4
//    chains run concurrently on the CU's 4 SIMDs, overlapping sync stalls.
//  - 128 WGs x 256 thr (1 WG/CU, 73KB LDS). WG = 32-pc slice (8 j). Wave:
//    16 rows x 32 pc x K=1024 via 16x16x32 MFMA (A regs, U-frag LDS 64KB).
//  - NO intra-WG barriers in the loop: z/h relays via wave-private LDS +
//    lgkmcnt(0); sync via per-(chain,step,WG) FLAG words (plain sc0sc1
//    stores, no atomic RMW); consumers poll 128 flags w/ dwordx4 sc0sc1.
//    Per-wave vmcnt(0) orders h-stores before the flag.
//  - h: sc0sc1 stores -> L3; readers normal cached loads (per-step-unique
//    slots, first-touch-after-write; cross-dispatch L2 inv proven r6-r10).
// ---------------------------------------------------------------------------

typedef __attribute__((ext_vector_type(8))) short short8;
typedef __attribute__((ext_vector_type(4))) short short4v;
typedef __attribute__((ext_vector_type(4))) float f32x4;
typedef __attribute__((ext_vector_type(4))) int int4v;
typedef unsigned short ushort_t;

__device__ __forceinline__ void lgkm0() {
  asm volatile("s_waitcnt lgkmcnt(0)" ::: "memory");
}

__device__ __forceinline__ ushort_t f2b(float f) {
  __hip_bfloat16 h = __float2bfloat16(f);
  return *reinterpret_cast<ushort_t*>(&h);
}
__device__ __forceinline__ float b2f(ushort_t u) {
  unsigned int x = ((unsigned int)u) << 16;
  return __builtin_bit_cast(float, x);
}
__device__ __forceinline__ float fsigmoid(float x) {
  return 1.f / (1.f + __expf(-x));
}
__device__ __forceinline__ float ftanh(float x) {
  return 1.f - 2.f / (__expf(2.f * x) + 1.f);
}

// device-coherent (L1/L2-bypass) accessors
__device__ __forceinline__ void store16_sc(ushort_t* p, short8 v) {
  asm volatile("global_store_dwordx4 %0, %1, off sc0 sc1"
               :: "v"(p), "v"(v) : "memory");
}
__device__ __forceinline__ void store4_sc(unsigned* p, unsigned v) {
  asm volatile("global_store_dword %0, %1, off sc0 sc1"
               :: "v"(p), "v"(v) : "memory");
}
__device__ __forceinline__ int4v load4_sc(const unsigned* p) {
  int4v r;
  asm volatile("global_load_dwordx4 %0, %1, off sc0 sc1"
               : "=v"(r) : "v"(p) : "memory");
  asm volatile("s_waitcnt vmcnt(0)" ::: "memory");
  return r;
}

__device__ __forceinline__ void gload_lds16(const ushort_t* g, ushort_t* l) {
  __builtin_amdgcn_global_load_lds(
      (const __attribute__((address_space(1))) unsigned int*)g,
      (__attribute__((address_space(3))) unsigned int*)l, 16, 0, 0);
}

// ---- convert W [K][4096] f32 -> [pc][k] bf16 (GEMM B-operand) -------------
__global__ __launch_bounds__(256) void k_convert(
    const float* __restrict__ src, ushort_t* __restrict__ dst, int kshift) {
  size_t tid = (size_t)blockIdx.x * 256 + threadIdx.x;  // = k*4096 + c
  int k = (int)(tid >> 12);
  int c = (int)(tid & 4095);
  int pc = ((c & 1023) << 2) | (c >> 10);
  dst[((size_t)pc << kshift) + k] = f2b(src[tid]);
}

// ---- convert U [1024][4096] f32 -> per-slice(32pc) 16x16 frag order -------
// cid = ((ws*2+tp)*32+ks)*64+l: pc = ws*32+tp*16+(l&15), k = ks*32+(l>>4)*8+e
__global__ __launch_bounds__(256) void k_convert_u(
    const float* __restrict__ src, ushort_t* __restrict__ dst) {
  int cid = blockIdx.x * 256 + threadIdx.x;   // 524288 chunks
  int l = cid & 63;
  int ks = (cid >> 6) & 31;
  int tp = (cid >> 11) & 1;
  int ws = cid >> 12;                          // 0..127
  int pc = ws * 32 + tp * 16 + (l & 15);
  int c = ((pc & 3) << 10) | (pc >> 2);
  int k0 = ks * 32 + (l >> 4) * 8;
  short8 v;
#pragma unroll
  for (int e = 0; e < 8; ++e)
    v[e] = (short)f2b(src[(size_t)(k0 + e) * 4096 + c]);
  *(short8*)(dst + (size_t)cid * 8) = v;
}

// ---- permute biases -------------------------------------------------------
__global__ __launch_bounds__(256) void k_bias(
    const float* __restrict__ b0, const float* __restrict__ b1,
    float* __restrict__ bp0, float* __restrict__ bp1) {
  int pc = blockIdx.x * 256 + threadIdx.x;
  int c = ((pc & 3) << 10) | (pc >> 2);
  bp0[pc] = b0[c];
  bp1[pc] = b1[c];
}

// ---- embedding gather: plain row-major Xef[8192][256] ---------------------
__global__ __launch_bounds__(256) void k_gather(
    const int* __restrict__ tokens, const float* __restrict__ emb,
    ushort_t* __restrict__ Xef) {
  int row = blockIdx.x;            // row = t*64 + b
  int t = row >> 6, b = row & 63;
  int tok = tokens[b * 128 + t];
  int d = threadIdx.x;
  Xef[(size_t)row * 256 + d] = f2b(emb[(size_t)tok * 256 + d]);
}

// ---- state init: h0 -> hall slot0; c0 -> c_st; zero flags -----------------
__global__ __launch_bounds__(256) void k_init(
    const float* __restrict__ h0, const float* __restrict__ c0,
    ushort_t* __restrict__ hall, float* __restrict__ c_st,
    unsigned* __restrict__ flg) {
  int tid = blockIdx.x * 256 + threadIdx.x;   // 65536 threads
  c_st[tid] = c0[tid];
  hall[tid] = f2b(h0[tid]);
  flg[tid] = 0;                                // layer0 flags (64K words)
  flg[65536 + tid] = 0;                        // layer1 flags
}

// ---- GEMM: C[8192][4096] = A[8192][K] * BT[4096][K]^T ---------------------
template <int NKS, int LAY>
__global__ __launch_bounds__(256) void k_gemm(
    const ushort_t* __restrict__ Af, const ushort_t* __restrict__ BT,
    ushort_t* __restrict__ C) {
  const int K = NKS * 16;
  const int xcd = blockIdx.x & 7, loc = blockIdx.x >> 3;
  const int wgM = xcd * 8 + (loc & 7);
  const int wgN = loc >> 3;
  const int tid = threadIdx.x;
  const int l = tid & 63;
  const int wv = tid >> 6;
  const int wvM = wv & 1, wvN = wv >> 1;

  __shared__ __align__(16) ushort_t Alds[4096];
  __shared__ __align__(16) ushort_t Blds[4096];

  const int m0 = wgM * 128, n0 = wgN * 128;
  f32x4 acc[4][4] = {};

  for (int k0 = 0; k0 < K; k0 += 32) {
    __syncthreads();
#pragma unroll
    for (int jj = 0; jj < 2; ++jj) {
      int c = jj * 256 + tid;
      int kc = c >> 7, r = c & 127;
      int R = m0 + r;
      int kcg = (k0 >> 3) + kc;
      const ushort_t* asrc =
          (LAY == 0) ? (Af + (size_t)R * 256 + kcg * 8)
                     : (Af + (size_t)(R >> 6) * 65536 + (R & 63) * 1024 + kcg * 8);
      gload_lds16(asrc, (ushort_t*)&Alds[(size_t)(jj * 256 + (tid & ~63)) * 8]);
      gload_lds16(BT + (size_t)(n0 + r) * K + k0 + kc * 8,
                  (ushort_t*)&Blds[(size_t)(jj * 256 + (tid & ~63)) * 8]);
    }
    __syncthreads();

    short8 af[4], bf[4];
#pragma unroll
    for (int mt = 0; mt < 4; ++mt)
      af[mt] = *(const short8*)&Alds[((l >> 4) * 128 + wvM * 64 + mt * 16 + (l & 15)) * 8];
#pragma unroll
    for (int nt = 0; nt < 4; ++nt)
      bf[nt] = *(const short8*)&Blds[((l >> 4) * 128 + wvN * 64 + nt * 16 + (l & 15)) * 8];
#pragma unroll
    for (int mt = 0; mt < 4; ++mt)
#pragma unroll
      for (int nt = 0; nt < 4; ++nt)
        acc[mt][nt] =
            __builtin_amdgcn_mfma_f32_16x16x32_bf16(af[mt], bf[nt], acc[mt][nt], 0, 0, 0);
  }

  const int rr0 = wgM * 128 + wvM * 64 + (l >> 4) * 4;
  const int cc0 = wgN * 128 + wvN * 64 + (l & 15);
#pragma unroll
  for (int mt = 0; mt < 4; ++mt)
#pragma unroll
    for (int nt = 0; nt < 4; ++nt)
#pragma unroll
      for (int r = 0; r < 4; ++r)
        C[(size_t)(rr0 + mt * 16 + r) * 4096 + cc0 + nt * 16] =
            f2b(acc[mt][nt][r]);
}

// ---- persistent LSTM layer, wave-per-chain, plain launch <<<128,256>>> ----
// WG ws: pc [ws*32, +32) (j [ws*8,+8)). Wave w = chain w: rows [w*16,+16),
// full K=1024, 64x 16x16x32 MFMA (A reg, B = LDS U-frags). No intra-WG
// barriers in the loop; per-(chain,step,WG) flags; per-wave vmcnt drain.
template <int LAYER>
__global__ __launch_bounds__(256, 1) void k_pers(
    const ushort_t* __restrict__ Uf,    // frag order (k_convert_u)
    const ushort_t* __restrict__ XW,    // [8192][4096] bf16 row-major
    const float* __restrict__ bp,       // [4096] permuted bias
    ushort_t* __restrict__ hall,        // 129 slots x [64][1024] bf16
    float* __restrict__ c_st,           // [64][1024] f32
    float* __restrict__ outp,           // L1: d_out
    const float* __restrict__ gamma, const float* __restrict__ beta,
    const float* __restrict__ mean, const float* __restrict__ var,
    unsigned* __restrict__ flg) {       // this layer: [4][128][128] words
  const int ws = blockIdx.x;            // 0..127
  const int tid = threadIdx.x;
  const int l = tid & 63;
  const int w = tid >> 6;               // wave = chain

  __shared__ __align__(16) ushort_t Ulds[2][32][512];  // 64 KB U slice
  __shared__ float zrel[4][2][16][16];                 // 8 KB wave-private z
  __shared__ ushort_t hrel[4][16][8];                  // 1 KB wave-private h

  // ---- stage U slice (4096 x 16B) ----
  {
    const ushort_t* src = Uf + (size_t)ws * 32768;
    for (int i = tid; i < 4096; i += 256)
      *(short8*)((ushort_t*)Ulds + (size_t)i * 8) =
          *(const short8*)(src + (size_t)i * 8);
  }

  // ---- per-lane epilogue constants: 2 (b,j) pairs ----
  const int b_loc = l & 15;
  const int b = w * 16 + b_loc;
  const int kg = l >> 4;                // 0..3
  float creg[2], scl[2], sft[2];
  f32x4 biasv[2];
#pragma unroll
  for (int p = 0; p < 2; ++p) {
    const int jo = kg + 4 * p;
    const int j = ws * 8 + jo;
    creg[p] = c_st[b * 1024 + j];
    biasv[p] = *(const f32x4*)(bp + ws * 32 + jo * 4);
    if (LAYER == 1) {
      float inv = rsqrtf(var[j] + 1e-3f);
      scl[p] = inv * gamma[j];
      sft[p] = beta[j] - mean[j] * scl[p];
    }
  }

  __syncthreads();   // Ulds visible (only barrier; loop is barrier-free)

#pragma unroll 1
  for (int t = 0; t < 128; ++t) {
    const ushort_t* hin =
        hall + (size_t)((LAYER == 1 && t == 0) ? 128 : t) * 65536;
    ushort_t* hout = hall + (size_t)(t + 1) * 65536;

    // ---- poll chain-w flags of step t-1 (128 WGs; lanes 0..31 x 4) ----
    if (t > 0) {
      const unsigned* fb = flg + (((w << 7) + (t - 1)) << 7);
      for (;;) {
        int4v v = {1, 1, 1, 1};
        if (l < 32) v = load4_sc(fb + l * 4);
        bool ok = (v[0] == 1) & (v[1] == 1) & (v[2] == 1) & (v[3] == 1);
        if (__all(ok)) break;
        __builtin_amdgcn_s_sleep(1);
      }
    }

    // ---- A: 32 back-to-back 16B loads (rows of chain w, full K) ----
    const ushort_t* ab = hin + (size_t)b * 1024 + kg * 8;
    short8 ar[32];
#pragma unroll
    for (int ks = 0; ks < 32; ++ks)
      ar[ks] = *(const short8*)(ab + ks * 32);

    // ---- XW for this step (overlaps A-load latency) ----
    short4v xw[2];
#pragma unroll
    for (int p = 0; p < 2; ++p)
      xw[p] = *(const short4v*)(
          XW + ((size_t)(t * 64 + b) << 12) + ws * 32 + (kg + 4 * p) * 4);

    // ---- 64 MFMAs: 2 pc-tiles x 32 k-steps (A reg, B LDS) ----
    f32x4 acc[2][2] = {};
#pragma unroll
    for (int ks = 0; ks < 32; ++ks) {
      short8 a = ar[ks];
      short8 q0 = *(const short8*)&Ulds[0][ks][l * 8];
      acc[0][ks & 1] =
          __builtin_amdgcn_mfma_f32_16x16x32_bf16(a, q0, acc[0][ks & 1], 0, 0, 0);
      short8 q1 = *(const short8*)&Ulds[1][ks][l * 8];
      acc[1][ks & 1] =
          __builtin_amdgcn_mfma_f32_16x16x32_bf16(a, q1, acc[1][ks & 1], 0, 0, 0);
    }

    // ---- z relay via wave-private LDS (16x16 C layout: col=l&15,
    //      row=(l>>4)*4+r); no barrier, lgkmcnt only ----
#pragma unroll
    for (int tp = 0; tp < 2; ++tp)
#pragma unroll
      for (int r = 0; r < 4; ++r)
        zrel[w][tp][kg * 4 + r][b_loc] = acc[tp][0][r] + acc[tp][1][r];
    lgkm0();

    // ---- epilogue: 2 pairs/lane ----
    float hn[2];
#pragma unroll
    for (int p = 0; p < 2; ++p) {
      const int jo = kg + 4 * p;
      f32x4 zv = *(const f32x4*)&zrel[w][jo >> 2][b_loc][(jo & 3) * 4];
      float zi = zv[0] + b2f((ushort_t)xw[p][0]) + biasv[p][0];
      float zf = zv[1] + b2f((ushort_t)xw[p][1]) + biasv[p][1];
      float zg = zv[2] + b2f((ushort_t)xw[p][2]) + biasv[p][2];
      float zo = zv[3] + b2f((ushort_t)xw[p][3]) + biasv[p][3];
      float ii = fsigmoid(zi), ff = fsigmoid(zf), oo = fsigmoid(zo);
      float gg = ftanh(zg);
      creg[p] = ff * creg[p] + ii * gg;
      hn[p] = oo * ftanh(creg[p]);
      hrel[w][b_loc][jo] = f2b(hn[p]);
      if (LAYER == 1) {
        const int j = ws * 8 + jo;
        outp[((size_t)b * 128 + t) * 1024 + j] = hn[p] * scl[p] + sft[p];
        if (t == 127) {
          outp[8388608 + b * 1024 + j] = hn[p];
          outp[8454144 + b * 1024 + j] = creg[p];
        }
      } else if (t == 127) {
        c_st[b * 1024 + ws * 8 + jo] = creg[p];
      }
    }
    lgkm0();

    // ---- h out: lanes 0..15, one 16B device-coherent store each ----
    if (l < 16) {
      short8 v = *(const short8*)&hrel[w][l][0];
      store16_sc(hout + (size_t)(w * 16 + l) * 1024 + ws * 8, v);
    }

    // ---- drain this wave's stores, then flag (plain sc store, no RMW) ----
    asm volatile("s_waitcnt vmcnt(0)" ::: "memory");
    if (l == 0)
      store4_sc(flg + (((w << 7) + t) << 7) + ws, 1u);
  }
}

extern "C" void kernel_launch(void* const* d_in, const int* in_sizes, int n_in,
                              void* d_out, int out_size, void* d_ws,
                              size_t ws_size, hipStream_t stream) {
  const int* tokens = (const int*)d_in[0];
  const float* h0 = (const float*)d_in[1];
  const float* c0 = (const float*)d_in[2];
  const float* emb = (const float*)d_in[3];
  const float* W0 = (const float*)d_in[4];
  const float* U0 = (const float*)d_in[5];
  const float* b0 = (const float*)d_in[6];
  const float* W1 = (const float*)d_in[7];
  const float* U1 = (const float*)d_in[8];
  const float* b1 = (const float*)d_in[9];
  const float* gammap = (const float*)d_in[10];
  const float* betap = (const float*)d_in[11];
  const float* mmean = (const float*)d_in[12];
  const float* mvar = (const float*)d_in[13];

  char* ws = (char*)d_ws;
  ushort_t* Uc0 = (ushort_t*)(ws + 0);             //  8 MB frag U0
  ushort_t* Uc1 = (ushort_t*)(ws + 8388608);       //  8 MB frag U1
  ushort_t* W0f = (ushort_t*)(ws + 16777216);      //  2 MB [pc][256]
  ushort_t* W1f = (ushort_t*)(ws + 18874368);      //  8 MB [pc][1024]
  float* bp0 = (float*)(ws + 27262976);            // 16 KB
  float* bp1 = (float*)(ws + 27279360);            // 16 KB
  ushort_t* Xef = (ushort_t*)(ws + 27295744);      //  4 MB [8192][256]
  ushort_t* XW = (ushort_t*)(ws + 31490048);       // 64 MB [8192][4096]
  ushort_t* hall = (ushort_t*)(ws + 98598912);     // 16.5 MB: 129 x 128KB
  float* c_st = (float*)(ws + 115507200);          // 256 KB
  unsigned* flg = (unsigned*)(ws + 115769344);     // 512 KB: 2 x [4][128][128]

  k_convert_u<<<2048, 256, 0, stream>>>(U0, Uc0);
  k_convert_u<<<2048, 256, 0, stream>>>(U1, Uc1);
  k_convert<<<4096, 256, 0, stream>>>(W0, W0f, 8);
  k_convert<<<16384, 256, 0, stream>>>(W1, W1f, 10);
  k_bias<<<16, 256, 0, stream>>>(b0, b1, bp0, bp1);
  k_gather<<<8192, 256, 0, stream>>>(tokens, emb, Xef);
  k_init<<<256, 256, 0, stream>>>(h0, c0, hall, c_st, flg);

  float* outp = (float*)d_out;

  // ---- layer 0 ----
  k_gemm<16, 0><<<2048, 256, 0, stream>>>(Xef, W0f, XW);
  k_pers<0><<<128, 256, 0, stream>>>(Uc0, XW, bp0, hall, c_st, nullptr,
                                     nullptr, nullptr, nullptr, nullptr,
                                     flg);

  // ---- layer 1 (GEMM A = hall slots 1..128 = L0 outputs) ----
  k_gemm<64, 1><<<2048, 256, 0, stream>>>(hall + 65536, W1f, XW);
  k_pers<1><<<128, 256, 0, stream>>>(Uc1, XW, bp1, hall, c_st, outp, gammap,
                                     betap, mmean, mvar, flg + 65536);
}